// Round 2
// baseline (419.096 us; speedup 1.0000x reference)
//
#include <hip/hip_runtime.h>
#include <hip/hip_bf16.h>

// 6 layers of relu(spmm(graph, x@W+b)), B=256, NN=255 nodes.
// R17 = R15 with phase-1 restructured after the R16 post-mortem:
//  - R16 (direct-global frags, 0 barriers) REGRESSED 83->102us: LDS staging
//    was load-bearing (decouples slow global loads from frag reads).
//  - R17 keeps X staging but DOUBLE-BUFFERS it: write(cur) -> prefetch(next)
//    -> one barrier -> frag-read(cur).  nk1 barriers instead of 2*nk1.
//  - As (Wt) staging deleted: Wt is <=286KB, L2-hot, and the 16x16x32 B-frag
//    layout (lane = row l&15, k-granule (l>>4)*8) is a contiguous 16B read
//    from row-major global.  1-step register prefetch.
// LDS: Bs0+Bs1 = 2x16KB, overlaid by Ys (32KB) after phase 1 -> still 32KB.
// Ys rotation layout / phase 2 / epilogues byte-identical to R15.

#define NN 255
#define YCH 2048           // ushorts per Y k-chunk: 64 rows * 32

typedef __attribute__((ext_vector_type(8))) short short8;
typedef __attribute__((ext_vector_type(4))) float floatx4;

__device__ __forceinline__ float bf2f(ushort u) {
    union { uint u; float f; } c; c.u = ((uint)u) << 16; return c.f;
}
__device__ __forceinline__ ushort f2bf(float f) {
    union { float f; uint u; } c; c.f = f;
    uint u = c.u + 0x7fff + ((c.u >> 16) & 1);
    return (ushort)(u >> 16);
}
__device__ __forceinline__ short8 u4_frag(uint4 v) {
    union { uint4 u; short8 s; } c; c.u = v; return c.s;
}

// ---------------- graph preprocessing ----------------
__global__ void zero_k(int* p, int n) {
    int i = blockIdx.x * blockDim.x + threadIdx.x;
    if (i < n) p[i] = 0;
}

// per-edge: dense-S scatter + rowsum (f32 atomics)
__global__ void edge_k(const int* __restrict__ r0, const int* __restrict__ c0, const float* __restrict__ v0,
                       const int* __restrict__ r1, const int* __restrict__ c1, const float* __restrict__ v1,
                       const int* __restrict__ r2, const int* __restrict__ c2, const float* __restrict__ v2,
                       const int* __restrict__ r3, const int* __restrict__ c3, const float* __restrict__ v3,
                       float* Sd, float* rs, int nnz) {
    int gi = blockIdx.y;
    int e = blockIdx.x * blockDim.x + threadIdx.x;
    if (e >= nnz) return;
    const int* rr = gi == 0 ? r0 : gi == 1 ? r1 : gi == 2 ? r2 : r3;
    const int* cc = gi == 0 ? c0 : gi == 1 ? c1 : gi == 2 ? c2 : c3;
    const float* vv = gi == 0 ? v0 : gi == 1 ? v1 : gi == 2 ? v2 : v3;
    int r = rr[e], c = cc[e];
    float v = vv[e];
    atomicAdd(&Sd[gi * 65536 + r * 256 + c], v);
    atomicAdd(&rs[gi * 256 + r], v);
}

// merged converts: Sd->Sb (bf16) then 4 weight transposes (ladder on idx)
__device__ __forceinline__ void wpiece(const float* __restrict__ W, ushort* __restrict__ Wt,
                                       int K, int N, int Kpad, int idx) {
    int n = idx / Kpad, k = idx - n * Kpad;
    float v = (n < N && k < K) ? W[(size_t)k * N + n] : 0.f;
    Wt[idx] = f2bf(v);
}

__global__ void conv_k(const float* __restrict__ Sd, ushort* __restrict__ Sb,
                       const float* __restrict__ W1, ushort* __restrict__ Wt1,
                       const float* __restrict__ W2, ushort* __restrict__ Wt2,
                       const float* __restrict__ W3, ushort* __restrict__ Wt3,
                       const float* __restrict__ W4, ushort* __restrict__ Wt4) {
    int idx = blockIdx.x * blockDim.x + threadIdx.x;
    if (idx < 262144) { Sb[idx] = f2bf(Sd[idx]); return; }
    idx -= 262144;
    if (idx < 133120) { wpiece(W1, Wt1, 400, 300, 416, idx); return; }
    idx -= 133120;
    if (idx < 40960)  { wpiece(W2, Wt2, 300, 100, 320, idx); return; }
    idx -= 40960;
    if (idx < 40960)  { wpiece(W3, Wt3, 100, 300, 128, idx); return; }
    idx -= 40960;
    if (idx < 143360) { wpiece(W4, Wt4, 300, 400, 320, idx); }
}

// ---------------- L0 fused: spmm(F=2, dense Sd, f32) -> gemm K=2 + relu ----------------
__global__ __launch_bounds__(256) void l0_fused(const float* __restrict__ H,
                                                const float* __restrict__ Sd0,
                                                const float* __restrict__ W0,
                                                const float* __restrict__ b0,
                                                const float* __restrict__ rs0,
                                                ushort* __restrict__ Y) {
    __shared__ float hsh[512];      // H_b [256][2], slot 255 = 0
    __shared__ float ssh[512];      // spmm result [256][2]
    int b = blockIdx.x, t = threadIdx.x;
    if (t < NN) {
        hsh[t * 2]     = H[((size_t)b * NN + t) * 2];
        hsh[t * 2 + 1] = H[((size_t)b * NN + t) * 2 + 1];
    } else {
        hsh[t * 2] = 0.f; hsh[t * 2 + 1] = 0.f;
    }
    __syncthreads();
    const float4* Sr = (const float4*)(Sd0 + (size_t)t * 256);
    float s0 = 0.f, s1 = 0.f;
    #pragma unroll 8
    for (int c4 = 0; c4 < 64; ++c4) {
        float4 v = Sr[c4];
        const float2* hp = (const float2*)&hsh[c4 * 8];
        float2 h0 = hp[0], h1 = hp[1], h2 = hp[2], h3 = hp[3];
        s0 = fmaf(v.x, h0.x, s0); s1 = fmaf(v.x, h0.y, s1);
        s0 = fmaf(v.y, h1.x, s0); s1 = fmaf(v.y, h1.y, s1);
        s0 = fmaf(v.z, h2.x, s0); s1 = fmaf(v.z, h2.y, s1);
        s0 = fmaf(v.w, h3.x, s0); s1 = fmaf(v.w, h3.y, s1);
    }
    ssh[t * 2] = s0; ssh[t * 2 + 1] = s1;
    __syncthreads();
    uint* out = (uint*)(Y + (((size_t)b) << 8) * 416);
    for (int i = 0; i < 200; ++i) {
        int idx = i * 256 + t;
        int m = idx / 200, n2 = idx - m * 200;
        int n = n2 * 2;
        float x0 = ssh[m * 2], x1 = ssh[m * 2 + 1];
        float rsm = rs0[m];
        float y0 = fmaf(x0, W0[n],     fmaf(x1, W0[400 + n],     rsm * b0[n]));
        float y1 = fmaf(x0, W0[n + 1], fmaf(x1, W0[400 + n + 1], rsm * b0[n + 1]));
        out[(size_t)m * 208 + n2] =
            (uint)f2bf(fmaxf(y0, 0.f)) | ((uint)f2bf(fmaxf(y1, 0.f)) << 16);
    }
}

// =======================================================================
// Fused layer: block = (batch b, 64-feature tile ft).
//   phase 1: Y[64f,256c] = Wt_tile @ X_b^T + bias
//            X staged in double-buffered LDS (1 barrier/k-step),
//            Wt frags direct from global (L2-hot), 1-step reg prefetch.
//   phase 2: Z[256r,64f] = relu(S @ Y)   (S global dbuf'd in regs, Y in LDS)
// LDS layout (rotation): row stride 32 ushorts (64B); 16B granule g of row r
// lives at position (g + (r>>2))&3. All frag ops are aligned b128/b64.
// =======================================================================
__global__ __launch_bounds__(256, 3) void fused_layer(const ushort* __restrict__ X,
                                                      const ushort* __restrict__ Wt,
                                                      const ushort* __restrict__ Sg,
                                                      const float* __restrict__ bias,
                                                      ushort* __restrict__ Z,
                                                      int Kpad, int Nfeat, int FsN,
                                                      int nft) {
    __shared__ ushort smem[8 * YCH];     // 32768 B -> LDS allows 5 blocks/CU
    ushort* Bs0 = smem;                  // [256][32] X staging, buffer 0
    ushort* Bs1 = smem + 8192;           // [256][32] X staging, buffer 1
    ushort* Ys  = smem;                  // overlay after phase 1: 8 x [64][32]

    int li = blockIdx.x;
    int x = li & 7, rr = li >> 3;
    int ft = rr % nft, b = (rr / nft) * 8 + x;
    int f0 = ft * 64;

    int t = threadIdx.x;
    int w = t >> 6, lane = t & 63;
    int frow = lane & 15, quad = lane >> 4;
    int rot = ((quad + (frow >> 2)) & 3) * 8;   // frag-read granule offset (ushorts)

    // ---------------- phase 1 ----------------
    // X staging: thread t owns row t's 64B k-chunk (contiguous global load).
    const ushort* Xb = X + (((size_t)b) << 8) * (size_t)Kpad;
    const ushort* Bpt = Xb + (size_t)t * Kpad;
    int brot = (t >> 2) & 3;
    // Wt direct: wf[j] = row (f0 + j*16 + frow), k = ks*32 + quad*8 .. +8
    const ushort* Wp = Wt + ((size_t)(f0 + frow)) * (size_t)Kpad + quad * 8;

    floatx4 acc[4][4];   // acc[i][j]: i = c-tile (X rows), j = f-tile (Wt rows)
    #pragma unroll
    for (int i = 0; i < 4; ++i)
        #pragma unroll
        for (int j = 0; j < 4; ++j) acc[i][j] = (floatx4)0.f;

    const ushort* Bb0 = &Bs0[(w * 64 + frow) * 32 + rot];  // X frag base, buf 0
    const ushort* Bb1 = &Bs1[(w * 64 + frow) * 32 + rot];  // X frag base, buf 1

    int nk1 = Kpad >> 5;
    // preload k-chunk 0 (X staging regs + W frag regs)
    uint4 pb0 = *(const uint4*)(Bpt);
    uint4 pb1 = *(const uint4*)(Bpt + 8);
    uint4 pb2 = *(const uint4*)(Bpt + 16);
    uint4 pb3 = *(const uint4*)(Bpt + 24);
    uint4 pw0 = *(const uint4*)(Wp);
    uint4 pw1 = *(const uint4*)(Wp + 16 * (size_t)Kpad);
    uint4 pw2 = *(const uint4*)(Wp + 32 * (size_t)Kpad);
    uint4 pw3 = *(const uint4*)(Wp + 48 * (size_t)Kpad);

    for (int ks = 0; ks < nk1; ++ks) {
        // stage current chunk into Bs[ks&1] (safe: last readers of this buffer
        // finished their ds_reads before the previous iteration's barrier)
        ushort* BsW = ((ks & 1) ? Bs1 : Bs0) + t * 32;
        *(uint4*)(BsW + (((0 + brot) & 3) * 8)) = pb0;
        *(uint4*)(BsW + (((1 + brot) & 3) * 8)) = pb1;
        *(uint4*)(BsW + (((2 + brot) & 3) * 8)) = pb2;
        *(uint4*)(BsW + (((3 + brot) & 3) * 8)) = pb3;
        uint4 nw0, nw1, nw2, nw3;
        if (ks + 1 < nk1) {              // prefetch chunk ks+1 (in flight across barrier+MFMAs)
            int off = (ks + 1) * 32;
            pb0 = *(const uint4*)(Bpt + off);
            pb1 = *(const uint4*)(Bpt + off + 8);
            pb2 = *(const uint4*)(Bpt + off + 16);
            pb3 = *(const uint4*)(Bpt + off + 24);
            nw0 = *(const uint4*)(Wp + off);
            nw1 = *(const uint4*)(Wp + off + 16 * (size_t)Kpad);
            nw2 = *(const uint4*)(Wp + off + 32 * (size_t)Kpad);
            nw3 = *(const uint4*)(Wp + off + 48 * (size_t)Kpad);
        }
        __syncthreads();                 // staging of Bs[ks&1] visible
        const ushort* Bb = (ks & 1) ? Bb1 : Bb0;
        short8 xf[4], wf[4];
        wf[0] = u4_frag(pw0); wf[1] = u4_frag(pw1);
        wf[2] = u4_frag(pw2); wf[3] = u4_frag(pw3);
        #pragma unroll
        for (int i = 0; i < 4; ++i)
            xf[i] = u4_frag(*(const uint4*)(Bb + i * 16 * 32));
        __builtin_amdgcn_s_setprio(1);
        #pragma unroll
        for (int i = 0; i < 4; ++i)
            #pragma unroll
            for (int j = 0; j < 4; ++j)
                acc[i][j] = __builtin_amdgcn_mfma_f32_16x16x32_bf16(xf[i], wf[j], acc[i][j], 0, 0, 0);
        __builtin_amdgcn_s_setprio(0);
        pw0 = nw0; pw1 = nw1; pw2 = nw2; pw3 = nw3;
    }

    // issue phase-2 ks=0 S loads NOW: latency hides behind the epilogue barrier
    const ushort* Sp = Sg + (size_t)(w * 64 + frow) * 256 + quad * 8;
    uint4 ps[4];
    #pragma unroll
    for (int i = 0; i < 4; ++i) ps[i] = *(const uint4*)(Sp + i * 4096);

    __syncthreads();   // all phase-1 frag reads done before Ys overwrites Bs

    // epilogue 1 -> Ys: c = w*64+i*16+quad*4+r (4 consecutive -> b64 write),
    // f = j*16+frow. Rotation key K(f)=(f>>2)&3 = (frow>>2)&3 (j*16 == 0 mod 4).
    #pragma unroll
    for (int j = 0; j < 4; ++j) {
        int f = j * 16 + frow;
        float bv = (f0 + f < Nfeat) ? bias[f0 + f] : 0.f;
        #pragma unroll
        for (int i = 0; i < 4; ++i) {
            int chunk = 2 * w + (i >> 1);
            int gc = 2 * (i & 1) + (quad >> 1);
            int base = chunk * YCH + f * 32 + (((gc + (frow >> 2)) & 3) * 8) + (quad & 1) * 4;
            uint lo = (uint)f2bf(acc[i][j][0] + bv) | ((uint)f2bf(acc[i][j][1] + bv) << 16);
            uint hi = (uint)f2bf(acc[i][j][2] + bv) | ((uint)f2bf(acc[i][j][3] + bv) << 16);
            *(uint2*)(&Ys[base]) = make_uint2(lo, hi);
        }
    }
    __syncthreads();

    // ---------------- phase 2 (no barriers, S double-buffered) ----------------
    #pragma unroll
    for (int i = 0; i < 4; ++i)
        #pragma unroll
        for (int j = 0; j < 4; ++j) acc[i][j] = (floatx4)0.f;

    for (int ks = 0; ks < 8; ++ks) {
        uint4 pn[4];
        if (ks < 7) {
            #pragma unroll
            for (int i = 0; i < 4; ++i)
                pn[i] = *(const uint4*)(Sp + i * 4096 + (ks + 1) * 32);
        }
        short8 bf[4];
        #pragma unroll
        for (int j = 0; j < 4; ++j)
            bf[j] = u4_frag(*(const uint4*)(&Ys[ks * YCH + (j * 16 + frow) * 32 + rot]));
        __builtin_amdgcn_s_setprio(1);
        #pragma unroll
        for (int i = 0; i < 4; ++i) {
            short8 af = u4_frag(ps[i]);
            #pragma unroll
            for (int j = 0; j < 4; ++j)
                acc[i][j] = __builtin_amdgcn_mfma_f32_16x16x32_bf16(af, bf[j], acc[i][j], 0, 0, 0);
        }
        __builtin_amdgcn_s_setprio(0);
        #pragma unroll
        for (int i = 0; i < 4; ++i) ps[i] = pn[i];
    }

    // epilogue 2: r = w*64+i*16+quad*4+reg, f = j*16+frow (32B runs)
    #pragma unroll
    for (int i = 0; i < 4; ++i)
        #pragma unroll
        for (int r = 0; r < 4; ++r) {
            int rg = w * 64 + i * 16 + quad * 4 + r;
            ushort* Zr = Z + (size_t)((b << 8) + rg) * FsN + f0;
            #pragma unroll
            for (int j = 0; j < 4; ++j)
                Zr[j * 16 + frow] = f2bf(fmaxf(acc[i][j][r], 0.f));
        }
}

// ---------------- L5 fused: gemm N=2 (+bias) -> spmm(F=2, dense Sd) + relu ----------------
__global__ __launch_bounds__(256) void l5_fused(const ushort* __restrict__ X,
                                                const float* __restrict__ Sd2,
                                                const float* __restrict__ Wd2,
                                                const float* __restrict__ bd2,
                                                float* __restrict__ out) {
    __shared__ float ysh[512];
    int b = blockIdx.x, t = threadIdx.x;
    const uint4* Xr = (const uint4*)(X + ((size_t)((b << 8) + t)) * 448);
    const float4* Wp = (const float4*)Wd2;
    float a0 = bd2[0], a1 = bd2[1];
    for (int i = 0; i < 50; ++i) {
        uint4 p = Xr[i];
        uint pv[4] = {p.x, p.y, p.z, p.w};
        #pragma unroll
        for (int q = 0; q < 4; ++q) {
            float x0 = bf2f((ushort)(pv[q] & 0xffffu));
            float x1 = bf2f((ushort)(pv[q] >> 16));
            float4 w = Wp[i * 4 + q];
            a0 = fmaf(x0, w.x, a0); a1 = fmaf(x0, w.y, a1);
            a0 = fmaf(x1, w.z, a0); a1 = fmaf(x1, w.w, a1);
        }
    }
    ysh[t * 2] = a0; ysh[t * 2 + 1] = a1;
    __syncthreads();
    if (t < NN) {
        const float4* Sr = (const float4*)(Sd2 + (size_t)t * 256);
        float s0 = 0.f, s1 = 0.f;
        #pragma unroll 8
        for (int c4 = 0; c4 < 64; ++c4) {
            float4 v = Sr[c4];
            const float2* yp = (const float2*)&ysh[c4 * 8];
            float2 y0 = yp[0], y1 = yp[1], y2 = yp[2], y3 = yp[3];
            s0 = fmaf(v.x, y0.x, s0); s1 = fmaf(v.x, y0.y, s1);
            s0 = fmaf(v.y, y1.x, s0); s1 = fmaf(v.y, y1.y, s1);
            s0 = fmaf(v.z, y2.x, s0); s1 = fmaf(v.z, y2.y, s1);
            s0 = fmaf(v.w, y3.x, s0); s1 = fmaf(v.w, y3.y, s1);
        }
        out[((size_t)b * NN + t) * 2]     = fmaxf(s0, 0.f);
        out[((size_t)b * NN + t) * 2 + 1] = fmaxf(s1, 0.f);
    }
}

extern "C" void kernel_launch(void* const* d_in, const int* in_sizes, int n_in,
                              void* d_out, int out_size, void* d_ws, size_t ws_size,
                              hipStream_t stream) {
    const float* H = (const float*)d_in[0];
    const int*   g_rows[4] = {(const int*)d_in[1], (const int*)d_in[4], (const int*)d_in[7], (const int*)d_in[10]};
    const int*   g_cols[4] = {(const int*)d_in[2], (const int*)d_in[5], (const int*)d_in[8], (const int*)d_in[11]};
    const float* g_vals[4] = {(const float*)d_in[3], (const float*)d_in[6], (const float*)d_in[9], (const float*)d_in[12]};
    const float* W0  = (const float*)d_in[13]; const float* b0  = (const float*)d_in[14];
    const float* W1  = (const float*)d_in[15]; const float* b1  = (const float*)d_in[16];
    const float* W2  = (const float*)d_in[17]; const float* b2  = (const float*)d_in[18];
    const float* Wd0 = (const float*)d_in[19]; const float* bd0 = (const float*)d_in[20];
    const float* Wd1 = (const float*)d_in[21]; const float* bd1 = (const float*)d_in[22];
    const float* Wd2 = (const float*)d_in[23]; const float* bd2 = (const float*)d_in[24];
    float* out = (float*)d_out;

    const int nnz = in_sizes[1];
    const int B   = in_sizes[0] / (NN * 2);   // 256
    const int Mp  = B * 256;                  // 65536 (padded)

    // ---- workspace (ushort units) ----
    ushort* bufA = (ushort*)d_ws;                    // N-layout [Mp, <=448]
    ushort* bufB = bufA + (size_t)Mp * 448;          // N-layout [Mp, <=320]
    ushort* Wt1 = bufB + (size_t)Mp * 320;           // [320,416]
    ushort* Wt2 = Wt1 + 320 * 416;                   // [128,320]
    ushort* Wt3 = Wt2 + 128 * 320;                   // [320,128]
    ushort* Wt4 = Wt3 + 320 * 128;                   // [448,320]
    ushort* Sb  = Wt4 + 448 * 320;                   // 4 x [256,256] bf16
    float*  rs  = (float*)(Sb + 4 * 65536);          // 4*256
    float*  Sd  = rs + 4 * 256;                      // 4*65536
    const int ZN = 4 * 256 + 4 * 65536;

    // setup: 3 launches
    zero_k<<<(ZN + 255) / 256, 256, 0, stream>>>((int*)rs, ZN);
    edge_k<<<dim3((nnz + 255) / 256, 4), 256, 0, stream>>>(
        g_rows[0], g_cols[0], g_vals[0], g_rows[1], g_cols[1], g_vals[1],
        g_rows[2], g_cols[2], g_vals[2], g_rows[3], g_cols[3], g_vals[3],
        Sd, rs, nnz);
    conv_k<<<(620544 + 255) / 256, 256, 0, stream>>>(Sd, Sb, W1, Wt1, W2, Wt2, Wd0, Wt3, Wd1, Wt4);

    // L0: [2->400] g0, commuted spmm-first, fused.  H -> bufA[Mp,416]
    l0_fused<<<B, 256, 0, stream>>>(H, Sd + 0 * 65536, W0, b0, rs + 0, bufA);

    // L1: [400->300] g0.  bufA(K416) -> bufB(FsN 320), 5 f-tiles
    fused_layer<<<B * 5, 256, 0, stream>>>(bufA, Wt1, Sb + 0 * 65536, b1, bufB, 416, 300, 320, 5);
    // L2: [300->100] g1.  bufB(K320) -> bufA(FsN 128), 2 f-tiles
    fused_layer<<<B * 2, 256, 0, stream>>>(bufB, Wt2, Sb + 1 * 65536, b2, bufA, 320, 100, 128, 2);
    // L3: [100->300] g3.  bufA(K128) -> bufB(FsN 320), 5 f-tiles
    fused_layer<<<B * 5, 256, 0, stream>>>(bufA, Wt3, Sb + 3 * 65536, bd0, bufB, 128, 300, 320, 5);
    // L4: [300->400] g2.  bufB(K320) -> bufA(FsN 448), 7 f-tiles
    fused_layer<<<B * 7, 256, 0, stream>>>(bufB, Wt4, Sb + 2 * 65536, bd1, bufA, 320, 400, 448, 7);

    // L5: [400->2] g2, fused.  bufA(stride 448, K=400) -> out[B*255,2]
    l5_fused<<<B, 256, 0, stream>>>(bufA, Sd + 2 * 65536, Wd2, bd2, out);
}

// Round 3
// 362.230 us; speedup vs baseline: 1.1570x; 1.1570x over previous
//
#include <hip/hip_runtime.h>
#include <hip/hip_bf16.h>

// 6 layers of relu(spmm(graph, x@W+b)), B=256, NN=255 nodes.
// R18 = R15 (best, 83us L4) + single isolated change: BOTH stagings (As=Wt,
// Bs=X) double-buffered -> ONE barrier per k-step (was 2), prefetch issued
// before the barrier so global latency hides across barrier+frag-reads+MFMA.
// R16/R17 post-mortem: W-direct-from-global frags (+setprio) regressed 83->
// 102/103us -- all-LDS frag feed is load-bearing; no setprio here.
// LDS: 2x(4KB As + 16KB Bs) = 40KB, Ys(32KB) overlays after phase 1.
// Rotation layout / frag reads / epilogues / phase 2 byte-identical to R15.

#define NN 255
#define YCH 2048           // ushorts per Y k-chunk: 64 rows * 32

typedef __attribute__((ext_vector_type(8))) short short8;
typedef __attribute__((ext_vector_type(4))) float floatx4;

__device__ __forceinline__ float bf2f(ushort u) {
    union { uint u; float f; } c; c.u = ((uint)u) << 16; return c.f;
}
__device__ __forceinline__ ushort f2bf(float f) {
    union { float f; uint u; } c; c.f = f;
    uint u = c.u + 0x7fff + ((c.u >> 16) & 1);
    return (ushort)(u >> 16);
}
__device__ __forceinline__ short8 u4_frag(uint4 v) {
    union { uint4 u; short8 s; } c; c.u = v; return c.s;
}

// ---------------- graph preprocessing ----------------
__global__ void zero_k(int* p, int n) {
    int i = blockIdx.x * blockDim.x + threadIdx.x;
    if (i < n) p[i] = 0;
}

// per-edge: dense-S scatter + rowsum (f32 atomics)
__global__ void edge_k(const int* __restrict__ r0, const int* __restrict__ c0, const float* __restrict__ v0,
                       const int* __restrict__ r1, const int* __restrict__ c1, const float* __restrict__ v1,
                       const int* __restrict__ r2, const int* __restrict__ c2, const float* __restrict__ v2,
                       const int* __restrict__ r3, const int* __restrict__ c3, const float* __restrict__ v3,
                       float* Sd, float* rs, int nnz) {
    int gi = blockIdx.y;
    int e = blockIdx.x * blockDim.x + threadIdx.x;
    if (e >= nnz) return;
    const int* rr = gi == 0 ? r0 : gi == 1 ? r1 : gi == 2 ? r2 : r3;
    const int* cc = gi == 0 ? c0 : gi == 1 ? c1 : gi == 2 ? c2 : c3;
    const float* vv = gi == 0 ? v0 : gi == 1 ? v1 : gi == 2 ? v2 : v3;
    int r = rr[e], c = cc[e];
    float v = vv[e];
    atomicAdd(&Sd[gi * 65536 + r * 256 + c], v);
    atomicAdd(&rs[gi * 256 + r], v);
}

// merged converts: Sd->Sb (bf16) then 4 weight transposes (ladder on idx)
__device__ __forceinline__ void wpiece(const float* __restrict__ W, ushort* __restrict__ Wt,
                                       int K, int N, int Kpad, int idx) {
    int n = idx / Kpad, k = idx - n * Kpad;
    float v = (n < N && k < K) ? W[(size_t)k * N + n] : 0.f;
    Wt[idx] = f2bf(v);
}

__global__ void conv_k(const float* __restrict__ Sd, ushort* __restrict__ Sb,
                       const float* __restrict__ W1, ushort* __restrict__ Wt1,
                       const float* __restrict__ W2, ushort* __restrict__ Wt2,
                       const float* __restrict__ W3, ushort* __restrict__ Wt3,
                       const float* __restrict__ W4, ushort* __restrict__ Wt4) {
    int idx = blockIdx.x * blockDim.x + threadIdx.x;
    if (idx < 262144) { Sb[idx] = f2bf(Sd[idx]); return; }
    idx -= 262144;
    if (idx < 133120) { wpiece(W1, Wt1, 400, 300, 416, idx); return; }
    idx -= 133120;
    if (idx < 40960)  { wpiece(W2, Wt2, 300, 100, 320, idx); return; }
    idx -= 40960;
    if (idx < 40960)  { wpiece(W3, Wt3, 100, 300, 128, idx); return; }
    idx -= 40960;
    if (idx < 143360) { wpiece(W4, Wt4, 300, 400, 320, idx); }
}

// ---------------- L0 fused: spmm(F=2, dense Sd, f32) -> gemm K=2 + relu ----------------
__global__ __launch_bounds__(256) void l0_fused(const float* __restrict__ H,
                                                const float* __restrict__ Sd0,
                                                const float* __restrict__ W0,
                                                const float* __restrict__ b0,
                                                const float* __restrict__ rs0,
                                                ushort* __restrict__ Y) {
    __shared__ float hsh[512];      // H_b [256][2], slot 255 = 0
    __shared__ float ssh[512];      // spmm result [256][2]
    int b = blockIdx.x, t = threadIdx.x;
    if (t < NN) {
        hsh[t * 2]     = H[((size_t)b * NN + t) * 2];
        hsh[t * 2 + 1] = H[((size_t)b * NN + t) * 2 + 1];
    } else {
        hsh[t * 2] = 0.f; hsh[t * 2 + 1] = 0.f;
    }
    __syncthreads();
    const float4* Sr = (const float4*)(Sd0 + (size_t)t * 256);
    float s0 = 0.f, s1 = 0.f;
    #pragma unroll 8
    for (int c4 = 0; c4 < 64; ++c4) {
        float4 v = Sr[c4];
        const float2* hp = (const float2*)&hsh[c4 * 8];
        float2 h0 = hp[0], h1 = hp[1], h2 = hp[2], h3 = hp[3];
        s0 = fmaf(v.x, h0.x, s0); s1 = fmaf(v.x, h0.y, s1);
        s0 = fmaf(v.y, h1.x, s0); s1 = fmaf(v.y, h1.y, s1);
        s0 = fmaf(v.z, h2.x, s0); s1 = fmaf(v.z, h2.y, s1);
        s0 = fmaf(v.w, h3.x, s0); s1 = fmaf(v.w, h3.y, s1);
    }
    ssh[t * 2] = s0; ssh[t * 2 + 1] = s1;
    __syncthreads();
    uint* out = (uint*)(Y + (((size_t)b) << 8) * 416);
    for (int i = 0; i < 200; ++i) {
        int idx = i * 256 + t;
        int m = idx / 200, n2 = idx - m * 200;
        int n = n2 * 2;
        float x0 = ssh[m * 2], x1 = ssh[m * 2 + 1];
        float rsm = rs0[m];
        float y0 = fmaf(x0, W0[n],     fmaf(x1, W0[400 + n],     rsm * b0[n]));
        float y1 = fmaf(x0, W0[n + 1], fmaf(x1, W0[400 + n + 1], rsm * b0[n + 1]));
        out[(size_t)m * 208 + n2] =
            (uint)f2bf(fmaxf(y0, 0.f)) | ((uint)f2bf(fmaxf(y1, 0.f)) << 16);
    }
}

// =======================================================================
// Fused layer: block = (batch b, 64-feature tile ft).
//   phase 1: Y[64f,256c] = Wt_tile @ X_b^T + bias  (A=X, B=Wt; both staged
//            in double-buffered LDS, ONE barrier/k-step, prefetch issued
//            before the barrier -> in flight across barrier+reads+MFMA)
//   phase 2: Z[256r,64f] = relu(S @ Y)  (S global dbuf'd in regs, Y in LDS)
// LDS layout (rotation): row stride 32 ushorts (64B); 16B granule g of row r
// lives at position (g + (r>>2))&3. All frag ops are aligned b128/b64.
// =======================================================================
__global__ __launch_bounds__(256, 3) void fused_layer(const ushort* __restrict__ X,
                                                      const ushort* __restrict__ Wt,
                                                      const ushort* __restrict__ Sg,
                                                      const float* __restrict__ bias,
                                                      ushort* __restrict__ Z,
                                                      int Kpad, int Nfeat, int FsN,
                                                      int nft) {
    __shared__ ushort smem[20480];       // 40960 B: dbuf staging; Ys overlays
    ushort* As0 = smem;                  // [64][32]  Wt staging, buf 0
    ushort* Bs0 = smem + 2048;           // [256][32] X staging, buf 0
    ushort* As1 = smem + 10240;          // [64][32]  Wt staging, buf 1
    ushort* Bs1 = smem + 12288;          // [256][32] X staging, buf 1
    ushort* Ys  = smem;                  // overlay after phase 1: 8 x [64][32]

    int li = blockIdx.x;
    int x = li & 7, rr = li >> 3;
    int ft = rr % nft, b = (rr / nft) * 8 + x;
    int f0 = ft * 64;

    int t = threadIdx.x;
    int w = t >> 6, lane = t & 63;
    int frow = lane & 15, quad = lane >> 4;
    int rot = ((quad + (frow >> 2)) & 3) * 8;   // frag-read granule offset (ushorts)

    // ---------------- phase 1 ----------------
    const ushort* Xb = X + (((size_t)b) << 8) * (size_t)Kpad;
    const ushort* Apt = Wt + (size_t)(f0 + (t >> 2)) * Kpad + ((t & 3) * 8);
    const ushort* Bpt = Xb + (size_t)t * Kpad;
    int asw  = (t >> 2) * 32 + (((t & 3) + ((t >> 4) & 3)) & 3) * 8;
    int bsw  = t * 32;
    int brot = (t >> 2) & 3;

    floatx4 acc[4][4];   // acc[i][j]: i = c-tile (A=X rows), j = f-tile (B=Wt rows)
    #pragma unroll
    for (int i = 0; i < 4; ++i)
        #pragma unroll
        for (int j = 0; j < 4; ++j) acc[i][j] = (floatx4)0.f;

    int nk1 = Kpad >> 5;
    uint4 pa  = *(const uint4*)(Apt);
    uint4 pb0 = *(const uint4*)(Bpt);
    uint4 pb1 = *(const uint4*)(Bpt + 8);
    uint4 pb2 = *(const uint4*)(Bpt + 16);
    uint4 pb3 = *(const uint4*)(Bpt + 24);
    Apt += 32; Bpt += 32;

    for (int ks = 0; ks < nk1; ++ks) {
        // stage chunk ks into buffer ks&1 (safe with 1 barrier/iter: readers
        // of this buffer from iter ks-2 finished before barrier ks-1)
        ushort* Asb = (ks & 1) ? As1 : As0;
        ushort* Bsb = (ks & 1) ? Bs1 : Bs0;
        *(uint4*)(Asb + asw) = pa;
        *(uint4*)(Bsb + bsw + (((0 + brot) & 3) * 8)) = pb0;
        *(uint4*)(Bsb + bsw + (((1 + brot) & 3) * 8)) = pb1;
        *(uint4*)(Bsb + bsw + (((2 + brot) & 3) * 8)) = pb2;
        *(uint4*)(Bsb + bsw + (((3 + brot) & 3) * 8)) = pb3;
        if (ks + 1 < nk1) {              // prefetch chunk ks+1: in flight across
            pa  = *(const uint4*)(Apt);  // barrier + frag reads + MFMAs
            pb0 = *(const uint4*)(Bpt);
            pb1 = *(const uint4*)(Bpt + 8);
            pb2 = *(const uint4*)(Bpt + 16);
            pb3 = *(const uint4*)(Bpt + 24);
            Apt += 32; Bpt += 32;
        }
        __syncthreads();                 // staging of buffer ks&1 visible
        const ushort* Ab = Asb + frow * 32 + rot;              // Wt frag base
        const ushort* Bb = Bsb + (w * 64 + frow) * 32 + rot;   // X frag base
        short8 xf[4], wf[4];
        #pragma unroll
        for (int i = 0; i < 4; ++i) {
            xf[i] = u4_frag(*(const uint4*)(Bb + i * 16 * 32));   // A operand: X rows
            wf[i] = u4_frag(*(const uint4*)(Ab + i * 16 * 32));   // B operand: Wt rows
        }
        #pragma unroll
        for (int i = 0; i < 4; ++i)
            #pragma unroll
            for (int j = 0; j < 4; ++j)
                acc[i][j] = __builtin_amdgcn_mfma_f32_16x16x32_bf16(xf[i], wf[j], acc[i][j], 0, 0, 0);
    }

    // issue phase-2 ks=0 S loads NOW: latency hides behind the epilogue barrier
    const ushort* Sp = Sg + (size_t)(w * 64 + frow) * 256 + quad * 8;
    uint4 ps[4];
    #pragma unroll
    for (int i = 0; i < 4; ++i) ps[i] = *(const uint4*)(Sp + i * 4096);

    __syncthreads();   // all phase-1 frag reads done before Ys overwrites staging

    // epilogue 1 -> Ys: c = w*64+i*16+quad*4+r (4 consecutive -> b64 write),
    // f = j*16+frow. Rotation key K(f)=(f>>2)&3 = (frow>>2)&3 (j*16 == 0 mod 4).
    #pragma unroll
    for (int j = 0; j < 4; ++j) {
        int f = j * 16 + frow;
        float bv = (f0 + f < Nfeat) ? bias[f0 + f] : 0.f;
        #pragma unroll
        for (int i = 0; i < 4; ++i) {
            int chunk = 2 * w + (i >> 1);
            int gc = 2 * (i & 1) + (quad >> 1);
            int base = chunk * YCH + f * 32 + (((gc + (frow >> 2)) & 3) * 8) + (quad & 1) * 4;
            uint lo = (uint)f2bf(acc[i][j][0] + bv) | ((uint)f2bf(acc[i][j][1] + bv) << 16);
            uint hi = (uint)f2bf(acc[i][j][2] + bv) | ((uint)f2bf(acc[i][j][3] + bv) << 16);
            *(uint2*)(&Ys[base]) = make_uint2(lo, hi);
        }
    }
    __syncthreads();

    // ---------------- phase 2 (no barriers, S double-buffered) ----------------
    #pragma unroll
    for (int i = 0; i < 4; ++i)
        #pragma unroll
        for (int j = 0; j < 4; ++j) acc[i][j] = (floatx4)0.f;

    for (int ks = 0; ks < 8; ++ks) {
        uint4 pn[4];
        if (ks < 7) {
            #pragma unroll
            for (int i = 0; i < 4; ++i)
                pn[i] = *(const uint4*)(Sp + i * 4096 + (ks + 1) * 32);
        }
        short8 bf[4];
        #pragma unroll
        for (int j = 0; j < 4; ++j)
            bf[j] = u4_frag(*(const uint4*)(&Ys[ks * YCH + (j * 16 + frow) * 32 + rot]));
        #pragma unroll
        for (int i = 0; i < 4; ++i) {
            short8 af = u4_frag(ps[i]);
            #pragma unroll
            for (int j = 0; j < 4; ++j)
                acc[i][j] = __builtin_amdgcn_mfma_f32_16x16x32_bf16(af, bf[j], acc[i][j], 0, 0, 0);
        }
        #pragma unroll
        for (int i = 0; i < 4; ++i) ps[i] = pn[i];
    }

    // epilogue 2: r = w*64+i*16+quad*4+reg, f = j*16+frow (32B runs)
    #pragma unroll
    for (int i = 0; i < 4; ++i)
        #pragma unroll
        for (int r = 0; r < 4; ++r) {
            int rg = w * 64 + i * 16 + quad * 4 + r;
            ushort* Zr = Z + (size_t)((b << 8) + rg) * FsN + f0;
            #pragma unroll
            for (int j = 0; j < 4; ++j)
                Zr[j * 16 + frow] = f2bf(fmaxf(acc[i][j][r], 0.f));
        }
}

// ---------------- L5 fused: gemm N=2 (+bias) -> spmm(F=2, dense Sd) + relu ----------------
__global__ __launch_bounds__(256) void l5_fused(const ushort* __restrict__ X,
                                                const float* __restrict__ Sd2,
                                                const float* __restrict__ Wd2,
                                                const float* __restrict__ bd2,
                                                float* __restrict__ out) {
    __shared__ float ysh[512];
    int b = blockIdx.x, t = threadIdx.x;
    const uint4* Xr = (const uint4*)(X + ((size_t)((b << 8) + t)) * 448);
    const float4* Wp = (const float4*)Wd2;
    float a0 = bd2[0], a1 = bd2[1];
    for (int i = 0; i < 50; ++i) {
        uint4 p = Xr[i];
        uint pv[4] = {p.x, p.y, p.z, p.w};
        #pragma unroll
        for (int q = 0; q < 4; ++q) {
            float x0 = bf2f((ushort)(pv[q] & 0xffffu));
            float x1 = bf2f((ushort)(pv[q] >> 16));
            float4 w = Wp[i * 4 + q];
            a0 = fmaf(x0, w.x, a0); a1 = fmaf(x0, w.y, a1);
            a0 = fmaf(x1, w.z, a0); a1 = fmaf(x1, w.w, a1);
        }
    }
    ysh[t * 2] = a0; ysh[t * 2 + 1] = a1;
    __syncthreads();
    if (t < NN) {
        const float4* Sr = (const float4*)(Sd2 + (size_t)t * 256);
        float s0 = 0.f, s1 = 0.f;
        #pragma unroll 8
        for (int c4 = 0; c4 < 64; ++c4) {
            float4 v = Sr[c4];
            const float2* yp = (const float2*)&ysh[c4 * 8];
            float2 y0 = yp[0], y1 = yp[1], y2 = yp[2], y3 = yp[3];
            s0 = fmaf(v.x, y0.x, s0); s1 = fmaf(v.x, y0.y, s1);
            s0 = fmaf(v.y, y1.x, s0); s1 = fmaf(v.y, y1.y, s1);
            s0 = fmaf(v.z, y2.x, s0); s1 = fmaf(v.z, y2.y, s1);
            s0 = fmaf(v.w, y3.x, s0); s1 = fmaf(v.w, y3.y, s1);
        }
        out[((size_t)b * NN + t) * 2]     = fmaxf(s0, 0.f);
        out[((size_t)b * NN + t) * 2 + 1] = fmaxf(s1, 0.f);
    }
}

extern "C" void kernel_launch(void* const* d_in, const int* in_sizes, int n_in,
                              void* d_out, int out_size, void* d_ws, size_t ws_size,
                              hipStream_t stream) {
    const float* H = (const float*)d_in[0];
    const int*   g_rows[4] = {(const int*)d_in[1], (const int*)d_in[4], (const int*)d_in[7], (const int*)d_in[10]};
    const int*   g_cols[4] = {(const int*)d_in[2], (const int*)d_in[5], (const int*)d_in[8], (const int*)d_in[11]};
    const float* g_vals[4] = {(const float*)d_in[3], (const float*)d_in[6], (const float*)d_in[9], (const float*)d_in[12]};
    const float* W0  = (const float*)d_in[13]; const float* b0  = (const float*)d_in[14];
    const float* W1  = (const float*)d_in[15]; const float* b1  = (const float*)d_in[16];
    const float* W2  = (const float*)d_in[17]; const float* b2  = (const float*)d_in[18];
    const float* Wd0 = (const float*)d_in[19]; const float* bd0 = (const float*)d_in[20];
    const float* Wd1 = (const float*)d_in[21]; const float* bd1 = (const float*)d_in[22];
    const float* Wd2 = (const float*)d_in[23]; const float* bd2 = (const float*)d_in[24];
    float* out = (float*)d_out;

    const int nnz = in_sizes[1];
    const int B   = in_sizes[0] / (NN * 2);   // 256
    const int Mp  = B * 256;                  // 65536 (padded)

    // ---- workspace (ushort units) ----
    ushort* bufA = (ushort*)d_ws;                    // N-layout [Mp, <=448]
    ushort* bufB = bufA + (size_t)Mp * 448;          // N-layout [Mp, <=320]
    ushort* Wt1 = bufB + (size_t)Mp * 320;           // [320,416]
    ushort* Wt2 = Wt1 + 320 * 416;                   // [128,320]
    ushort* Wt3 = Wt2 + 128 * 320;                   // [320,128]
    ushort* Wt4 = Wt3 + 320 * 128;                   // [448,320]
    ushort* Sb  = Wt4 + 448 * 320;                   // 4 x [256,256] bf16
    float*  rs  = (float*)(Sb + 4 * 65536);          // 4*256
    float*  Sd  = rs + 4 * 256;                      // 4*65536
    const int ZN = 4 * 256 + 4 * 65536;

    // setup: 3 launches
    zero_k<<<(ZN + 255) / 256, 256, 0, stream>>>((int*)rs, ZN);
    edge_k<<<dim3((nnz + 255) / 256, 4), 256, 0, stream>>>(
        g_rows[0], g_cols[0], g_vals[0], g_rows[1], g_cols[1], g_vals[1],
        g_rows[2], g_cols[2], g_vals[2], g_rows[3], g_cols[3], g_vals[3],
        Sd, rs, nnz);
    conv_k<<<(620544 + 255) / 256, 256, 0, stream>>>(Sd, Sb, W1, Wt1, W2, Wt2, Wd0, Wt3, Wd1, Wt4);

    // L0: [2->400] g0, commuted spmm-first, fused.  H -> bufA[Mp,416]
    l0_fused<<<B, 256, 0, stream>>>(H, Sd + 0 * 65536, W0, b0, rs + 0, bufA);

    // L1: [400->300] g0.  bufA(K416) -> bufB(FsN 320), 5 f-tiles
    fused_layer<<<B * 5, 256, 0, stream>>>(bufA, Wt1, Sb + 0 * 65536, b1, bufB, 416, 300, 320, 5);
    // L2: [300->100] g1.  bufB(K320) -> bufA(FsN 128), 2 f-tiles
    fused_layer<<<B * 2, 256, 0, stream>>>(bufB, Wt2, Sb + 1 * 65536, b2, bufA, 320, 100, 128, 2);
    // L3: [100->300] g3.  bufA(K128) -> bufB(FsN 320), 5 f-tiles
    fused_layer<<<B * 5, 256, 0, stream>>>(bufA, Wt3, Sb + 3 * 65536, bd0, bufB, 128, 300, 320, 5);
    // L4: [300->400] g2.  bufB(K320) -> bufA(FsN 448), 7 f-tiles
    fused_layer<<<B * 7, 256, 0, stream>>>(bufB, Wt4, Sb + 2 * 65536, bd1, bufA, 320, 400, 448, 7);

    // L5: [400->2] g2, fused.  bufA(stride 448, K=400) -> out[B*255,2]
    l5_fused<<<B, 256, 0, stream>>>(bufA, Sd + 2 * 65536, Wd2, bd2, out);
}